// Round 1
// baseline (113.836 us; speedup 1.0000x reference)
//
#include <hip/hip_runtime.h>

#define DIM 768
#define NE 8
#define NTOK (128 * 197)      // 25216
#define TPW 8                 // tokens per wave
#define NWAVES (NTOK / TPW)   // 3152, exact

// One wave (64 lanes) per block; each wave handles TPW consecutive tokens.
// W held entirely in VGPRs (96 regs/lane), x streamed with 1-token prefetch.
__global__ __launch_bounds__(64) void router_kernel(
    const float* __restrict__ x,
    const float* __restrict__ W,
    const float* __restrict__ b,
    float* __restrict__ out)
{
    const int lane = threadIdx.x;        // 0..63
    const int wave = blockIdx.x;         // 0..NWAVES-1

    // After reduce-scatter, lane l owns expert e(l) = bitrev3(l&7).
    const int l3 = lane & 7;
    const int e_lane = ((l3 & 1) << 2) | (l3 & 2) | ((l3 >> 2) & 1);

    // W fragments: wreg[e][c] = W[e][c*256 + 4*lane .. +3]  (static indexing only)
    float4 wreg[NE][3];
#pragma unroll
    for (int e = 0; e < NE; ++e) {
#pragma unroll
        for (int c = 0; c < 3; ++c) {
            wreg[e][c] = *reinterpret_cast<const float4*>(W + e * DIM + c * 256 + lane * 4);
        }
    }
    const float bias = b[e_lane];

    int tok = wave * TPW;
    const float* xp = x + (size_t)tok * DIM + lane * 4;

    float4 cx0 = *reinterpret_cast<const float4*>(xp);
    float4 cx1 = *reinterpret_cast<const float4*>(xp + 256);
    float4 cx2 = *reinterpret_cast<const float4*>(xp + 512);

    for (int t = 0; t < TPW; ++t, ++tok) {
        // ---- prefetch next token's x (uniform branch; no OOB on last) ----
        const float* xn = xp + DIM;
        float4 nx0, nx1, nx2;
        if (t + 1 < TPW) {
            nx0 = *reinterpret_cast<const float4*>(xn);
            nx1 = *reinterpret_cast<const float4*>(xn + 256);
            nx2 = *reinterpret_cast<const float4*>(xn + 512);
        } else {
            nx0 = nx1 = nx2 = make_float4(0.f, 0.f, 0.f, 0.f);
        }

        // ---- per-lane partial dot for all 8 experts (96 FMA) ----
        float acc[NE];
#pragma unroll
        for (int e = 0; e < NE; ++e) {
            float a;
            a = cx0.x * wreg[e][0].x;
            a = fmaf(cx0.y, wreg[e][0].y, a);
            a = fmaf(cx0.z, wreg[e][0].z, a);
            a = fmaf(cx0.w, wreg[e][0].w, a);
            a = fmaf(cx1.x, wreg[e][1].x, a);
            a = fmaf(cx1.y, wreg[e][1].y, a);
            a = fmaf(cx1.z, wreg[e][1].z, a);
            a = fmaf(cx1.w, wreg[e][1].w, a);
            a = fmaf(cx2.x, wreg[e][2].x, a);
            a = fmaf(cx2.y, wreg[e][2].y, a);
            a = fmaf(cx2.z, wreg[e][2].z, a);
            a = fmaf(cx2.w, wreg[e][2].w, a);
            acc[e] = a;
        }

        // ---- reduce-scatter butterfly: 7 shuffles instead of 48 ----
        float r4[4];
        {
            const bool hi = (lane & 1) != 0;
#pragma unroll
            for (int k = 0; k < 4; ++k) {
                float send = hi ? acc[k] : acc[k + 4];
                float recv = __shfl_xor(send, 1, 64);
                r4[k] = (hi ? acc[k + 4] : acc[k]) + recv;
            }
        }
        float r2[2];
        {
            const bool hi = (lane & 2) != 0;
#pragma unroll
            for (int k = 0; k < 2; ++k) {
                float send = hi ? r2[0] * 0.f + r4[k] : r4[k + 2];  // see note below
                // (explicit form, no trickery:)
                send = hi ? r4[k] : r4[k + 2];
                float recv = __shfl_xor(send, 2, 64);
                r2[k] = (hi ? r4[k + 2] : r4[k]) + recv;
            }
        }
        float lg;
        {
            const bool hi = (lane & 4) != 0;
            float send = hi ? r2[0] : r2[1];
            float recv = __shfl_xor(send, 4, 64);
            lg = (hi ? r2[1] : r2[0]) + recv;
        }
        lg += __shfl_xor(lg, 8, 64);
        lg += __shfl_xor(lg, 16, 64);
        lg += __shfl_xor(lg, 32, 64);
        lg += bias;

        // ---- gather all 8 logits to every lane (uniform epilogue) ----
        float logit[NE];
#pragma unroll
        for (int e = 0; e < NE; ++e) {
            const int src = ((e & 1) << 2) | (e & 2) | ((e >> 2) & 1);  // bitrev3
            logit[e] = __shfl(lg, src, 64);
        }

        // ---- top-2 (stable: ties -> lower index, matching lax.top_k) ----
        float v1 = logit[0]; int i1 = 0;
        float v2 = -1e30f;   int i2 = 0;
#pragma unroll
        for (int e = 1; e < NE; ++e) {
            const float v = logit[e];
            const bool gt1 = v > v1;
            const bool gt2 = v > v2;
            v2 = gt1 ? v1 : (gt2 ? v : v2);
            i2 = gt1 ? i1 : (gt2 ? e : i2);
            v1 = gt1 ? v : v1;
            i1 = gt1 ? e : i1;
        }

        // ---- softmax values for the top-2 only ----
        float Z = 0.f;
#pragma unroll
        for (int e = 0; e < NE; ++e) Z += __expf(logit[e] - v1);
        const float g1 = 1.0f / Z;
        const float g2 = __expf(v2 - v1) / Z;

        if (lane == 0) {
            reinterpret_cast<float2*>(out)[tok] = make_float2(g1, g2);
        } else if (lane == 1) {
            reinterpret_cast<float2*>(out + 2 * (size_t)NTOK)[tok] =
                make_float2((float)i1, (float)i2);
        }

        cx0 = nx0; cx1 = nx1; cx2 = nx2;
        xp = xn;
    }
}

extern "C" void kernel_launch(void* const* d_in, const int* in_sizes, int n_in,
                              void* d_out, int out_size, void* d_ws, size_t ws_size,
                              hipStream_t stream) {
    const float* x = (const float*)d_in[0];   // [128,197,768] f32
    const float* W = (const float*)d_in[1];   // [8,768] f32
    const float* b = (const float*)d_in[2];   // [8] f32
    float* out = (float*)d_out;               // [NTOK*2] gates ++ [NTOK*2] idx(as f32)
    (void)in_sizes; (void)n_in; (void)out_size; (void)d_ws; (void)ws_size;

    router_kernel<<<NWAVES, 64, 0, stream>>>(x, W, b, out);
}

// Round 2
// 110.255 us; speedup vs baseline: 1.0325x; 1.0325x over previous
//
#include <hip/hip_runtime.h>

#define DIM 768
#define NE 8
#define NTOK (128 * 197)        // 25216
#define TPW 8                   // tokens per wave
#define NWAVES (NTOK / TPW)     // 3152, exact
#define WPB 4                   // waves per block
#define NBLK (NWAVES / WPB)     // 788, exact

// 4 independent waves per block (no __syncthreads). Each wave: TPW consecutive
// tokens, W held in VGPRs (96 regs/lane), x streamed with 1-token prefetch.
// __launch_bounds__(256,3): pin >=3 waves/EU (<=170 VGPR) -- occupancy guard.
__global__ __launch_bounds__(256, 3) void router_kernel(
    const float* __restrict__ x,
    const float* __restrict__ W,
    const float* __restrict__ b,
    float* __restrict__ out)
{
    const int lane = threadIdx.x & 63;
    const int wave = blockIdx.x * WPB + (threadIdx.x >> 6);   // 0..NWAVES-1

    // After reduce-scatter, lane l owns expert e(l) = bitrev3(l&7).
    const int l3 = lane & 7;
    const int e_lane = ((l3 & 1) << 2) | (l3 & 2) | ((l3 >> 2) & 1);

    // W fragments: wreg[e][c] = W[e][c*256 + 4*lane .. +3]  (static indexing)
    float4 wreg[NE][3];
#pragma unroll
    for (int e = 0; e < NE; ++e) {
#pragma unroll
        for (int c = 0; c < 3; ++c) {
            wreg[e][c] = *reinterpret_cast<const float4*>(W + e * DIM + c * 256 + lane * 4);
        }
    }
    const float bias = b[e_lane];

    const int tok0 = wave * TPW;
    const float* xp = x + (size_t)tok0 * DIM + lane * 4;

    float4 cx0 = *reinterpret_cast<const float4*>(xp);
    float4 cx1 = *reinterpret_cast<const float4*>(xp + 256);
    float4 cx2 = *reinterpret_cast<const float4*>(xp + 512);

    float2 rg = make_float2(0.f, 0.f);   // lanes 0..7: token (tok0+lane) gates
    float2 ri = make_float2(0.f, 0.f);   // lanes 0..7: token (tok0+lane) indices

    for (int t = 0; t < TPW; ++t) {
        // ---- prefetch next token's x (clamped on last iter; always valid) ----
        const float* xn = (t + 1 < TPW) ? xp + DIM : xp;
        float4 nx0 = *reinterpret_cast<const float4*>(xn);
        float4 nx1 = *reinterpret_cast<const float4*>(xn + 256);
        float4 nx2 = *reinterpret_cast<const float4*>(xn + 512);

        // ---- per-lane partial dot for all 8 experts (96 FMA) ----
        float acc[NE];
#pragma unroll
        for (int e = 0; e < NE; ++e) {
            float a;
            a = cx0.x * wreg[e][0].x;
            a = fmaf(cx0.y, wreg[e][0].y, a);
            a = fmaf(cx0.z, wreg[e][0].z, a);
            a = fmaf(cx0.w, wreg[e][0].w, a);
            a = fmaf(cx1.x, wreg[e][1].x, a);
            a = fmaf(cx1.y, wreg[e][1].y, a);
            a = fmaf(cx1.z, wreg[e][1].z, a);
            a = fmaf(cx1.w, wreg[e][1].w, a);
            a = fmaf(cx2.x, wreg[e][2].x, a);
            a = fmaf(cx2.y, wreg[e][2].y, a);
            a = fmaf(cx2.z, wreg[e][2].z, a);
            a = fmaf(cx2.w, wreg[e][2].w, a);
            acc[e] = a;
        }

        // ---- reduce-scatter butterfly (7 shuffles instead of 48) ----
        float r4[4];
        {
            const bool hi = (lane & 1) != 0;
#pragma unroll
            for (int k = 0; k < 4; ++k) {
                float send = hi ? acc[k] : acc[k + 4];
                float recv = __shfl_xor(send, 1, 64);
                r4[k] = (hi ? acc[k + 4] : acc[k]) + recv;
            }
        }
        float r2[2];
        {
            const bool hi = (lane & 2) != 0;
#pragma unroll
            for (int k = 0; k < 2; ++k) {
                float send = hi ? r4[k] : r4[k + 2];
                float recv = __shfl_xor(send, 2, 64);
                r2[k] = (hi ? r4[k + 2] : r4[k]) + recv;
            }
        }
        float lg;
        {
            const bool hi = (lane & 4) != 0;
            float send = hi ? r2[0] : r2[1];
            float recv = __shfl_xor(send, 4, 64);
            lg = (hi ? r2[1] : r2[0]) + recv;
        }
        lg += __shfl_xor(lg, 8, 64);
        lg += __shfl_xor(lg, 16, 64);
        lg += __shfl_xor(lg, 32, 64);
        lg += bias;

        // ---- gather all 8 logits to every lane (uniform epilogue) ----
        float logit[NE];
#pragma unroll
        for (int e = 0; e < NE; ++e) {
            const int src = ((e & 1) << 2) | (e & 2) | ((e >> 2) & 1);  // bitrev3
            logit[e] = __shfl(lg, src, 64);
        }

        // ---- top-2 (stable: ties -> lower index, matching lax.top_k) ----
        float v1 = logit[0]; int i1 = 0;
        float v2 = -1e30f;   int i2 = 0;
#pragma unroll
        for (int e = 1; e < NE; ++e) {
            const float v = logit[e];
            const bool gt1 = v > v1;
            const bool gt2 = v > v2;
            v2 = gt1 ? v1 : (gt2 ? v : v2);
            i2 = gt1 ? i1 : (gt2 ? e : i2);
            v1 = gt1 ? v : v1;
            i1 = gt1 ? e : i1;
        }

        // ---- softmax values for the top-2 only ----
        float Z = 0.f;
#pragma unroll
        for (int e = 0; e < NE; ++e) Z += __expf(logit[e] - v1);
        const float g1 = 1.0f / Z;
        const float g2 = __expf(v2 - v1) / Z;

        // ---- park token t's result in lane t (2 cndmasks, no store yet) ----
        if (lane == t) {
            rg = make_float2(g1, g2);
            ri = make_float2((float)i1, (float)i2);
        }

        cx0 = nx0; cx1 = nx1; cx2 = nx2;
        xp = xn;
    }

    // ---- two coalesced dwordx2 stores per wave ----
    if (lane < TPW) {
        reinterpret_cast<float2*>(out)[tok0 + lane] = rg;
        reinterpret_cast<float2*>(out + 2 * (size_t)NTOK)[tok0 + lane] = ri;
    }
}

extern "C" void kernel_launch(void* const* d_in, const int* in_sizes, int n_in,
                              void* d_out, int out_size, void* d_ws, size_t ws_size,
                              hipStream_t stream) {
    const float* x = (const float*)d_in[0];   // [128,197,768] f32
    const float* W = (const float*)d_in[1];   // [8,768] f32
    const float* b = (const float*)d_in[2];   // [8] f32
    float* out = (float*)d_out;               // [NTOK*2] gates ++ [NTOK*2] idx(as f32)
    (void)in_sizes; (void)n_in; (void)out_size; (void)d_ws; (void)ws_size;

    router_kernel<<<NBLK, WPB * 64, 0, stream>>>(x, W, b, out);
}